// Round 12
// baseline (523.068 us; speedup 1.0000x reference)
//
#include <hip/hip_runtime.h>
#include <math.h>

#define W_ 160
#define H_ 128
#define C_ 32
#define D_ 96
#define NPIX (H_*W_)          // 20480

// ---------------- workspace layout ----------------
// floats: part @0 (5,898,240) | wT @5,898,240 (864) | rot @5,899,104+ (24)
// bytes : var (fp16 pairs, chunk-planed) @ 23,596,544, size 125,829,120
#define OFF_PART    0
#define OFF_WT      5898240
#define OFF_ROT     5899104
#define OFF_VAR_BYTES  23596544ull
#define VAR_BYTES      125829120ull

typedef unsigned int uint;

__device__ inline uint pack2(float a, float b) {
    unsigned short ua = __builtin_bit_cast(unsigned short, (_Float16)a);
    unsigned short ub = __builtin_bit_cast(unsigned short, (_Float16)b);
    return (uint)ua | ((uint)ub << 16);
}
__device__ inline float f16lo(uint u){ return (float)__builtin_bit_cast(_Float16,(unsigned short)(u & 0xffffu)); }
__device__ inline float f16hi(uint u){ return (float)__builtin_bit_cast(_Float16,(unsigned short)(u >> 16)); }

// ---------------------------------------------------------------------------
// 1 block: weight transpose [c][27] -> [27][c] + projection prep
__global__ __launch_bounds__(256) void k_prep(
    const float* __restrict__ proj,
    const float* __restrict__ wsrc,
    float* __restrict__ wT,
    float* __restrict__ rotrans)
{
    int t = threadIdx.x;
    for (int i = t; i < 864; i += 256) {
        int s = i >> 5, c = i & 31;          // s = (kd*3+kh)*3+kw
        wT[i] = wsrc[c * 27 + s];
    }
    if (t == 0) {
        float P[3][16];
        for (int v = 0; v < 3; ++v) {
            const float* E = proj + v * 32;
            const float* K = proj + v * 32 + 16;
            for (int i = 0; i < 3; ++i)
                for (int j = 0; j < 4; ++j)
                    P[v][i*4+j] = K[i*4+0]*E[0*4+j] + K[i*4+1]*E[1*4+j] + K[i*4+2]*E[2*4+j];
            for (int j = 0; j < 4; ++j) P[v][12+j] = E[12+j];
        }
        const float* m = P[0];
        float inv[16];
        inv[0]  =  m[5]*m[10]*m[15] - m[5]*m[11]*m[14] - m[9]*m[6]*m[15] + m[9]*m[7]*m[14] + m[13]*m[6]*m[11] - m[13]*m[7]*m[10];
        inv[4]  = -m[4]*m[10]*m[15] + m[4]*m[11]*m[14] + m[8]*m[6]*m[15] - m[8]*m[7]*m[14] - m[12]*m[6]*m[11] + m[12]*m[7]*m[10];
        inv[8]  =  m[4]*m[9]*m[15]  - m[4]*m[11]*m[13] - m[8]*m[5]*m[15] + m[8]*m[7]*m[13] + m[12]*m[5]*m[11] - m[12]*m[7]*m[9];
        inv[12] = -m[4]*m[9]*m[14]  + m[4]*m[10]*m[13] + m[8]*m[5]*m[14] - m[8]*m[6]*m[13] - m[12]*m[5]*m[10] + m[12]*m[6]*m[9];
        inv[1]  = -m[1]*m[10]*m[15] + m[1]*m[11]*m[14] + m[9]*m[2]*m[15] - m[9]*m[3]*m[14] - m[13]*m[2]*m[11] + m[13]*m[3]*m[10];
        inv[5]  =  m[0]*m[10]*m[15] - m[0]*m[11]*m[14] - m[8]*m[2]*m[15] + m[8]*m[3]*m[14] + m[12]*m[2]*m[11] - m[12]*m[3]*m[10];
        inv[9]  = -m[0]*m[9]*m[15]  + m[0]*m[11]*m[13] + m[8]*m[1]*m[15] - m[8]*m[3]*m[13] - m[12]*m[1]*m[11] + m[12]*m[3]*m[9];
        inv[13] =  m[0]*m[9]*m[14]  - m[0]*m[10]*m[13] - m[8]*m[1]*m[14] + m[8]*m[2]*m[13] + m[12]*m[1]*m[10] - m[12]*m[2]*m[9];
        inv[2]  =  m[1]*m[6]*m[15]  - m[1]*m[7]*m[14]  - m[5]*m[2]*m[15] + m[5]*m[3]*m[14] + m[13]*m[2]*m[7]  - m[13]*m[3]*m[6];
        inv[6]  = -m[0]*m[6]*m[15]  + m[0]*m[7]*m[14]  + m[4]*m[2]*m[15] - m[4]*m[3]*m[14] - m[12]*m[2]*m[7]  + m[12]*m[3]*m[6];
        inv[10] =  m[0]*m[5]*m[15]  - m[0]*m[7]*m[13]  - m[4]*m[1]*m[15] + m[4]*m[3]*m[13] + m[12]*m[1]*m[7]  - m[12]*m[3]*m[5];
        inv[14] = -m[0]*m[5]*m[14]  + m[0]*m[6]*m[13]  + m[4]*m[1]*m[14] - m[4]*m[2]*m[13] - m[12]*m[1]*m[6]  + m[12]*m[2]*m[5];
        inv[3]  = -m[1]*m[6]*m[11]  + m[1]*m[7]*m[10]  + m[5]*m[2]*m[11] - m[5]*m[3]*m[10] - m[9]*m[2]*m[7]   + m[9]*m[3]*m[6];
        inv[7]  =  m[0]*m[6]*m[11]  - m[0]*m[7]*m[10]  - m[4]*m[2]*m[11] + m[4]*m[3]*m[10] + m[8]*m[2]*m[7]   - m[8]*m[3]*m[6];
        inv[11] = -m[0]*m[5]*m[11]  + m[0]*m[7]*m[9]   + m[4]*m[1]*m[11] - m[4]*m[3]*m[9]  - m[8]*m[1]*m[7]   + m[8]*m[3]*m[5];
        inv[15] =  m[0]*m[5]*m[10]  - m[0]*m[6]*m[9]   - m[4]*m[1]*m[10] + m[4]*m[2]*m[9]  + m[8]*m[1]*m[6]   - m[8]*m[2]*m[5];
        float det = m[0]*inv[0] + m[1]*inv[4] + m[2]*inv[8] + m[3]*inv[12];
        float rdet = 1.0f / det;
        for (int i = 0; i < 16; ++i) inv[i] *= rdet;

        for (int v = 1; v < 3; ++v) {
            float M[16];
            for (int i = 0; i < 4; ++i)
                for (int j = 0; j < 4; ++j) {
                    float a = 0.f;
                    for (int k = 0; k < 4; ++k) a += P[v][i*4+k] * inv[k*4+j];
                    M[i*4+j] = a;
                }
            float* o = rotrans + (v-1)*12;
            for (int i = 0; i < 3; ++i) {
                for (int j = 0; j < 3; ++j) o[i*3+j] = M[i*4+j];
                o[9+i] = M[i*4+3];
            }
        }
    }
}

// ---------------------------------------------------------------------------
// Variance, channel-SPLIT: one thread = (pixel, depth, 8-channel chunk).
// 4x more waves than r9, 72 loads/thread (was 288) -> deeper TLP latency
// hiding. Var volume is chunk-planed: [ds][chunk][pix][4 uints] so stores
// stay lane-contiguous. Weight math duplicated x4 (VALU was 22% busy - free).
__global__ __launch_bounds__(256) void k_var(
    const float* __restrict__ fea,
    const float* __restrict__ rotrans_g,
    const float* __restrict__ dvals,
    uint* __restrict__ varU)
{
    const int tid = threadIdx.x;
    const int bx = blockIdx.x, by = blockIdx.y, ds = blockIdx.z;
    const int chunk = tid >> 6;            // 0..3 -> channels chunk*8..+7
    const int lane = tid & 63;
    const int gx = bx * 8 + (lane & 7);
    const int gy = by * 8 + (lane >> 3);
    const float dv = dvals[ds];

    const int ro = gy * W_ + gx;           // ref plane (v=0), channel 0
    float w[2][4];
    int   off[2][4];
    const float xf = (float)gx, yf = (float)gy;
    #pragma unroll
    for (int v = 0; v < 2; ++v) {
        const float* rt = rotrans_g + v * 12;
        float A0 = rt[0]*xf + rt[1]*yf + rt[2];
        float A1 = rt[3]*xf + rt[4]*yf + rt[5];
        float A2 = rt[6]*xf + rt[7]*yf + rt[8];
        float X = A0 * dv + rt[9];
        float Y = A1 * dv + rt[10];
        float Z = A2 * dv + rt[11];
        float rz = __builtin_amdgcn_rcpf(Z);
        float pxf = X * rz, pyf = Y * rz;
        float x0f = floorf(pxf), y0f = floorf(pyf);
        float fx = pxf - x0f, fy = pyf - y0f;
        float w00 = (1.f-fx)*(1.f-fy), w10 = fx*(1.f-fy);
        float w01 = (1.f-fx)*fy,       w11 = fx*fy;
        float x1f = x0f + 1.f, y1f = y0f + 1.f;
        bool vx0 = (x0f >= 0.f) && (x0f <= (float)(W_-1));
        bool vx1 = (x1f >= 0.f) && (x1f <= (float)(W_-1));
        bool vy0 = (y0f >= 0.f) && (y0f <= (float)(H_-1));
        bool vy1 = (y1f >= 0.f) && (y1f <= (float)(H_-1));
        w[v][0] = (vx0 && vy0) ? w00 : 0.f;
        w[v][1] = (vx1 && vy0) ? w10 : 0.f;
        w[v][2] = (vx0 && vy1) ? w01 : 0.f;
        w[v][3] = (vx1 && vy1) ? w11 : 0.f;
        int xc0 = (int)fminf(fmaxf(x0f, 0.f), (float)(W_-1));
        int xc1 = (int)fminf(fmaxf(x1f, 0.f), (float)(W_-1));
        int yc0 = (int)fminf(fmaxf(y0f, 0.f), (float)(H_-1));
        int yc1 = (int)fminf(fmaxf(y1f, 0.f), (float)(H_-1));
        const int vb = (v + 1) * C_ * NPIX;
        off[v][0] = vb + yc0 * W_ + xc0;
        off[v][1] = vb + yc0 * W_ + xc1;
        off[v][2] = vb + yc1 * W_ + xc0;
        off[v][3] = vb + yc1 * W_ + xc1;
    }

    const float inv3 = 1.f / 3.f;
    uint outv[4];
    const int c0 = chunk * 8;
    #pragma unroll
    for (int j = 0; j < 4; ++j) {
        float vr[2];
        #pragma unroll
        for (int h = 0; h < 2; ++h) {
            const float* pc = fea + (size_t)(c0 + 2*j + h) * NPIX;
            float s = pc[ro];
            float q = s * s;
            #pragma unroll
            for (int v = 0; v < 2; ++v) {
                float f00 = pc[off[v][0]], f10 = pc[off[v][1]];
                float f01 = pc[off[v][2]], f11 = pc[off[v][3]];
                float wf = w[v][0]*f00 + w[v][1]*f10 + w[v][2]*f01 + w[v][3]*f11;
                s += wf;
                q += wf * wf;
            }
            float mm = s * inv3;
            vr[h] = q * inv3 - mm * mm;
        }
        outv[j] = pack2(vr[0], vr[1]);
    }
    uint4* dst = (uint4*)(varU + ((size_t)(ds * 4 + chunk) * NPIX + gy * W_ + gx) * 4);
    *dst = *(uint4*)outv;
}

// ---------------------------------------------------------------------------
// 3x3x3 conv as 3 kd-plane partials from one var slice. Staging re-indexed
// for the chunk-planed var layout (chunk-major item split, coalesced/plane).
#define HSB 19
#define NHP (18*HSB)   // 342
#define PSTR 20        // uints per point in LDS (16 data + 4 pad)

__global__ __launch_bounds__(256) void k_conv(
    const uint* __restrict__ varU,
    const float* __restrict__ wT,
    float* __restrict__ part)
{
    __shared__ uint  sL[NHP * PSTR];   // 27,360 B
    __shared__ float4 sW[216];          // 3,456 B

    const int tid = threadIdx.x;
    const int bx = blockIdx.x, by = blockIdx.y, ds = blockIdx.z;

    for (int i = tid; i < 216; i += 256) sW[i] = ((const float4*)wT)[i];
    for (int i = tid; i < NHP * 4; i += 256) {
        const int chunk = i / NHP;
        const int p = i - chunk * NHP;
        const int py = p / HSB;
        const int px = p - py * HSB;
        if (px < 18) {
            const int gy = by * 16 + py - 1;
            const int gx = bx * 16 + px - 1;
            uint4* d = (uint4*)&sL[p * PSTR + chunk * 4];
            if (gy < 0 || gy >= H_ || gx < 0 || gx >= W_) {
                *d = make_uint4(0u,0u,0u,0u);
            } else {
                *d = *(const uint4*)(varU + ((size_t)(ds * 4 + chunk) * NPIX + gy * W_ + gx) * 4);
            }
        }
    }
    __syncthreads();

    const int ty = tid >> 4, tx = tid & 15;
    float acc[3] = {0.f, 0.f, 0.f};
    #pragma unroll
    for (int c4 = 0; c4 < 8; ++c4) {
        #pragma unroll
        for (int kh = 0; kh < 3; ++kh) {
            float4 wv[3][3];
            #pragma unroll
            for (int kd = 0; kd < 3; ++kd)
                #pragma unroll
                for (int kw = 0; kw < 3; ++kw)
                    wv[kd][kw] = sW[((kd*3 + kh)*3 + kw) * 8 + c4];
            const int rowb = (ty + kh) * HSB + tx;
            #pragma unroll
            for (int kw = 0; kw < 3; ++kw) {
                const uint* u = &sL[(rowb + kw) * PSTR + c4 * 2];
                uint u0 = u[0], u1 = u[1];
                float f0 = f16lo(u0), f1 = f16hi(u0);
                float f2 = f16lo(u1), f3 = f16hi(u1);
                #pragma unroll
                for (int kd = 0; kd < 3; ++kd)
                    acc[kd] += f0*wv[kd][kw].x + f1*wv[kd][kw].y
                             + f2*wv[kd][kw].z + f3*wv[kd][kw].w;
            }
        }
    }
    const int oy = by * 16 + ty;
    const int ox = bx * 16 + tx;
    #pragma unroll
    for (int kd = 0; kd < 3; ++kd)
        part[(size_t)(kd * D_ + ds) * NPIX + oy * W_ + ox] = acc[kd];
}

// ---------------------------------------------------------------------------
__global__ __launch_bounds__(256) void k_softmax(
    const float* __restrict__ part,
    const float* __restrict__ dvals,
    const float* __restrict__ bias,
    float* __restrict__ out)
{
    __shared__ float sD[96];
    if (threadIdx.x < 96) sD[threadIdx.x] = dvals[threadIdx.x];
    __syncthreads();

    int pix = blockIdx.x * 256 + threadIdx.x;
    if (pix >= NPIX) return;
    float e[96];
    const float b = bias[0];
    float m = -1e30f;
    #pragma unroll
    for (int d = 0; d < 96; ++d) {
        float c = part[(size_t)(D_ + d) * NPIX + pix];              // kd=1 plane
        if (d > 0)  c += part[(size_t)(d - 1) * NPIX + pix];        // kd=0 plane
        if (d < 95) c += part[(size_t)(2*D_ + d + 1) * NPIX + pix]; // kd=2 plane
        c += b;
        e[d] = c;
        m = fmaxf(m, c);
    }
    float sum = 0.f, dsum = 0.f, isum = 0.f;
    #pragma unroll
    for (int d = 0; d < 96; ++d) {
        float ex = __expf(e[d] - m);
        e[d] = ex;
        sum  += ex;
        dsum += ex * sD[d];
        isum += ex * (float)d;
    }
    float inv = 1.f / sum;
    float depth = dsum * inv;
    float idxf = isum * inv;
    int di = (int)idxf;
    di = di < 0 ? 0 : (di > 95 ? 95 : di);
    float cs = 0.f;
    #pragma unroll
    for (int d = 0; d < 96; ++d) {
        bool in = (d >= di - 1) && (d <= di + 2);
        cs += in ? e[d] : 0.f;
    }
    out[pix] = depth;
    out[NPIX + pix] = cs * inv;
}

// ---------------------------------------------------------------------------
extern "C" void kernel_launch(void* const* d_in, const int* in_sizes, int n_in,
                              void* d_out, int out_size, void* d_ws, size_t ws_size,
                              hipStream_t stream)
{
    const float* features = (const float*)d_in[0];
    const float* proj     = (const float*)d_in[1];
    const float* dvals    = (const float*)d_in[2];
    const float* wsrc     = (const float*)d_in[3];
    const float* bias     = (const float*)d_in[4];
    float* ws = (float*)d_ws;
    float* part    = ws + OFF_PART;
    float* wT      = ws + OFF_WT;
    float* rotrans = ws + OFF_ROT;
    uint*  varU    = (uint*)((char*)d_ws + OFF_VAR_BYTES);
    float* out = (float*)d_out;

    hipLaunchKernelGGL(k_prep, dim3(1), dim3(256), 0, stream, proj, wsrc, wT, rotrans);
    hipLaunchKernelGGL(k_var, dim3(20, 16, 96), dim3(256), 0, stream,
                       features, rotrans, dvals, varU);
    hipLaunchKernelGGL(k_conv, dim3(10, 8, 96), dim3(256), 0, stream,
                       varU, wT, part);
    hipLaunchKernelGGL(k_softmax, dim3(80), dim3(256), 0, stream, part, dvals, bias, out);
}